// Round 16
// baseline (194.996 us; speedup 1.0000x reference)
//
#include <hip/hip_runtime.h>
#include <stdint.h>

// Problem: out[m][n] = sum_k x[m][k] * w[n][k] + bias[n]
//   M=256, N=16384, K=4096, w = dequant(2-bit, group=16 along k)
// Round 16: ZERO-BARRIER self-sufficient waves. r12/r15 proved time is
// invariant to waves/domains/barrier-count -> the phase-locked structure is
// the floor. Here every wave (64m x 32n x full K) is independent:
//  - q2 loaded COALESCED by the consuming wave itself: lane l <- uint4 pair
//    for (row l&31, kg (l>>5)*2, +1): 32 x 64B fully-consumed lines per tile
//    (fixes round 5's 8B-segment gather disease).
//  - dequant in-lane (same deq8/v_perm), then in-WAVE transpose through a
//    private 4KB x 2 LDS scratch: write fragment-ordered, lgkmcnt(0), read
//    as MFMA B-frags. No s_barrier anywhere.
//  - A reg-prefetched from the coalesced fragment workspace (L1-shared by
//    the block's 4 same-m waves); q2/nrm prefetched 2 tiles deep.
// Cost: dequant x4 chip-wide (~+3us VALU). Gain: no phase floor.
// Grid (128,4) x 256 thr = 2048 waves; LDS 32KB/block; launch_bounds(256,2).
#define M_DIM 256
#define N_DIM 16384
#define K_DIM 4096
#define NT 64   // k-tiles of 64

typedef __bf16 bf16x8 __attribute__((ext_vector_type(8)));
typedef float  f32x4  __attribute__((ext_vector_type(4)));

// fp32 -> bf16 bits, round-nearest-even (finite inputs)
__device__ __forceinline__ uint32_t f2bf(float f) {
  uint32_t u = __float_as_uint(f);
  return (u + 0x7fffu + ((u >> 16) & 1u)) >> 16;
}

// ---------------------------------------------------------------------------
// Kernel 1: x fp32 [256][4096] -> bf16 fragment-chunk order (unchanged).
// Chunk = (m-block of 16 rows) x (k-chunk of 32): 64 slots x 16B.
// Slot L holds row (L&15), k = (L>>4)*8 .. +7  (MFMA 16x16x32 A-frag order).
// ws uint4 index = (mb_glob*128 + kch)*64 + L.
// ---------------------------------------------------------------------------
__global__ __launch_bounds__(256) void cvt_x_kernel(const float* __restrict__ x,
                                                    uint4* __restrict__ ws) {
  int T = blockIdx.x * 256 + threadIdx.x;       // 0..131071
  int mb_glob = T >> 13;                        // 16 m-blocks
  int r       = T & 8191;
  int kch     = r >> 6;                         // 128 k-chunks
  int L       = r & 63;
  int row = mb_glob * 16 + (L & 15);
  int k   = kch * 32 + (L >> 4) * 8;
  const float* p = x + (size_t)row * K_DIM + k;
  float4 a = *(const float4*)p;
  float4 b = *(const float4*)(p + 4);
  uint4 o;
  o.x = f2bf(a.x) | (f2bf(a.y) << 16);
  o.y = f2bf(a.z) | (f2bf(a.w) << 16);
  o.z = f2bf(b.x) | (f2bf(b.y) << 16);
  o.w = f2bf(b.z) | (f2bf(b.w) << 16);
  ws[T] = o;
}

// ---------------------------------------------------------------------------
// Dequant 8 elems (2 packed q2 words; 4 crumbs in each low byte) of one group.
// Table entries {-n, a-n, 2a-n, 3a-n}, a = n*2/3 -- bit-identical to the
// fmaf+f2bf reference path.  v_perm_b32 picks the bf16 entry per crumb.
// ---------------------------------------------------------------------------
__device__ __forceinline__ uint4 deq8(uint32_t qx, uint32_t qy, uint32_t tlo,
                                      uint32_t thi) {
  uint32_t s0 = ((qx & 3u) | ((qx & 0xCu) << 14)) * 0x0202u + 0x01000100u;
  uint32_t s1 = (((qx >> 4) & 3u) | ((qx & 0xC0u) << 10)) * 0x0202u + 0x01000100u;
  uint32_t s2 = ((qy & 3u) | ((qy & 0xCu) << 14)) * 0x0202u + 0x01000100u;
  uint32_t s3 = (((qy >> 4) & 3u) | ((qy & 0xC0u) << 10)) * 0x0202u + 0x01000100u;
  uint4 r;
  r.x = __builtin_amdgcn_perm(thi, tlo, s0);
  r.y = __builtin_amdgcn_perm(thi, tlo, s1);
  r.z = __builtin_amdgcn_perm(thi, tlo, s2);
  r.w = __builtin_amdgcn_perm(thi, tlo, s3);
  return r;
}

// ---------------------------------------------------------------------------
// Kernel 2: grid (128,4), 256 threads = 4 independent waves.
// Wave w: rows m0..+63 (m0 = blockIdx.y*64), cols n0w..+31
// (n0w = blockIdx.x*128 + w*32), full K. Private scratch Sc[w][2][256]
// (2 x 4KB ping-pong). Per tile T:
//   1. prefetch A(T+1) frags (8x uint4, ping-pong regs)
//   2. 4 ds_read_b128 B-frags of tile T from scratch[T&1]
//   3. dequant q(T+1) (regs, loaded 2 tiles ago) -> 4 ds_write to [T&1 ^ 1]
//   4. reload q(T+3) + nrm(T+3)
//   5. 16 MFMA;  6. lgkmcnt(0) (in-wave write->read ordering). NO barriers.
// ---------------------------------------------------------------------------
__global__ __launch_bounds__(256, 2) void gemm2bit_kernel(
    const uint4*    __restrict__ aws,  // A chunks (see cvt)
    const uint32_t* __restrict__ q2,   // [G][4] packed 2-bit (low byte crumbs)
    const float*    __restrict__ nrm,  // [G] group norms (f32)
    const float*    __restrict__ bias, // [N]
    float*          __restrict__ out)  // [256][16384] fp32
{
  __shared__ uint4 Sc[4][2][256];   // per-wave 2 x 4KB scratch = 32 KiB

  const int tid  = threadIdx.x;
  const int lane = tid & 63;
  const int w    = tid >> 6;        // 0..3
  const int lo4  = lane & 15;
  const int qd   = lane >> 4;
  const int rr   = lane & 31;       // q2 row within wave's 32-n slab
  const int khi  = lane >> 5;       // kg base = khi*2
  const int n0w  = blockIdx.x * 128 + w * 32;
  const int m0   = blockIdx.y * 64;

  uint4 (*scr)[256] = Sc[w];

  // A frag source: m-chunk mb = blockIdx.y*4 + mc, k-chunk c:
  //   pA[mc*8192 + c*64]
  const uint4* pA = aws + (size_t)(blockIdx.y * 4) * 8192 + lane;

  // q2: lane handles groups (row rr, kg khi*2) and (row rr, kg khi*2+1).
  // word offset of tile T: pq + T*16 (and +4 for the second group).
  const uint32_t* pq = q2 + ((size_t)(n0w + rr) * 256 + khi * 2) * 4;
  const float*    pn = nrm + (size_t)(n0w + rr) * 256;   // float4 at +T*4

  // scratch write base: chunk cid = lane>>4 (= (khi*2>>1)*2 + (rr>>4)),
  // slots +0,+16 (group kg even), +32,+48 (kg odd)
  const int wbase = (lane >> 4) * 64 + lo4;

  f32x4 acc[4][2];
#pragma unroll
  for (int mc = 0; mc < 4; ++mc)
#pragma unroll
    for (int u = 0; u < 2; ++u)
      acc[mc][u] = (f32x4){0.f, 0.f, 0.f, 0.f};

  // dequant tile (2 groups/lane) -> 4 ds_write_b128 into scratch[PP]
#define DEQ_WRITE(PP, Q1, Q2v, N4)                                             \
  do {                                                                         \
    float nv1 = khi ? (N4).z : (N4).x;                                         \
    float nv2 = khi ? (N4).w : (N4).y;                                         \
    float a1 = nv1 * (2.0f / 3.0f);                                            \
    uint32_t t1lo = f2bf(-nv1) | (f2bf(fmaf(1.0f, a1, -nv1)) << 16);           \
    uint32_t t1hi = f2bf(fmaf(2.0f, a1, -nv1)) |                               \
                    (f2bf(fmaf(3.0f, a1, -nv1)) << 16);                        \
    scr[PP][wbase]      = deq8((Q1).x, (Q1).y, t1lo, t1hi);                    \
    scr[PP][wbase + 16] = deq8((Q1).z, (Q1).w, t1lo, t1hi);                    \
    float a2 = nv2 * (2.0f / 3.0f);                                            \
    uint32_t t2lo = f2bf(-nv2) | (f2bf(fmaf(1.0f, a2, -nv2)) << 16);           \
    uint32_t t2hi = f2bf(fmaf(2.0f, a2, -nv2)) |                               \
                    (f2bf(fmaf(3.0f, a2, -nv2)) << 16);                        \
    scr[PP][wbase + 32] = deq8((Q2v).x, (Q2v).y, t2lo, t2hi);                  \
    scr[PP][wbase + 48] = deq8((Q2v).z, (Q2v).w, t2lo, t2hi);                  \
  } while (0)

  uint4 afE[8], afO[8];   // [mc*2+ts], ping-pong
  uint4 qA1, qA2, qB1, qB2;
  float4 nA4, nB4;

  // ---- prologue: A(0); dequant tile 0 -> scratch[0]; q(1)->A, q(2)->B ----
#pragma unroll
  for (int mc = 0; mc < 4; ++mc)
#pragma unroll
    for (int ts = 0; ts < 2; ++ts)
      afE[mc * 2 + ts] = pA[(size_t)mc * 8192 + ts * 64];
  {
    uint4 q01 = *(const uint4*)pq;
    uint4 q02 = *(const uint4*)(pq + 4);
    float4 n04 = *(const float4*)pn;
    qA1 = *(const uint4*)(pq + 16);  qA2 = *(const uint4*)(pq + 20);
    nA4 = *(const float4*)(pn + 4);
    qB1 = *(const uint4*)(pq + 32);  qB2 = *(const uint4*)(pq + 36);
    nB4 = *(const float4*)(pn + 8);
    DEQ_WRITE(0, q01, q02, n04);
  }
  asm volatile("s_waitcnt lgkmcnt(0)" ::: "memory");
  __builtin_amdgcn_sched_barrier(0);

  // Body T: reads scratch[T&1] (tile T); writes tile T+1 -> [T&1 ^1];
  // reloads q(T+3). In-wave lgkmcnt(0) at end orders writes before the
  // next body's reads. NO cross-wave sync.
#define BODY(T, PP, AFC, AFN, Q1, Q2v, N4)                                     \
  do {                                                                         \
    if ((T) + 1 < NT) {                                                        \
      _Pragma("unroll")                                                        \
      for (int mc = 0; mc < 4; ++mc)                                           \
        _Pragma("unroll")                                                      \
        for (int ts = 0; ts < 2; ++ts)                                         \
          AFN[mc * 2 + ts] = pA[(size_t)mc * 8192 + (((T) + 1) * 2 + ts) * 64];\
    }                                                                          \
    bf16x8 bfv[4];                                                             \
    _Pragma("unroll")                                                          \
    for (int c = 0; c < 4; ++c)                                                \
      bfv[c] = *(const bf16x8*)&scr[PP][c * 64 + lane];                        \
    if ((T) + 1 < NT) DEQ_WRITE((PP) ^ 1, Q1, Q2v, N4);                        \
    if ((T) + 3 < NT) {                                                        \
      Q1  = *(const uint4*)(pq + ((T) + 3) * 16);                              \
      Q2v = *(const uint4*)(pq + ((T) + 3) * 16 + 4);                          \
      N4  = *(const float4*)(pn + ((T) + 3) * 4);                              \
    }                                                                          \
    _Pragma("unroll")                                                          \
    for (int mc = 0; mc < 4; ++mc)                                             \
      _Pragma("unroll")                                                        \
      for (int ts = 0; ts < 2; ++ts) {                                         \
        bf16x8 av = __builtin_bit_cast(bf16x8, AFC[mc * 2 + ts]);              \
        _Pragma("unroll")                                                      \
        for (int u = 0; u < 2; ++u)                                            \
          acc[mc][u] = __builtin_amdgcn_mfma_f32_16x16x32_bf16(av,             \
                           bfv[ts * 2 + u], acc[mc][u], 0, 0, 0);              \
      }                                                                        \
    asm volatile("s_waitcnt lgkmcnt(0)" ::: "memory");                         \
    __builtin_amdgcn_sched_barrier(0);                                         \
  } while (0)

  for (int t2 = 0; t2 < NT; t2 += 2) {
    BODY(t2,     0, afE, afO, qA1, qA2, nA4);
    BODY(t2 + 1, 1, afO, afE, qB1, qB2, nB4);
  }
#undef BODY
#undef DEQ_WRITE

  // ---- epilogue: direct store + bias. C/D: col=lane&15 (n),
  // row=(lane>>4)*4+reg (m). ----
  float bv[2];
#pragma unroll
  for (int u = 0; u < 2; ++u)
    bv[u] = bias[n0w + u * 16 + lo4];
#pragma unroll
  for (int mc = 0; mc < 4; ++mc) {
    int mrow = m0 + mc * 16 + qd * 4;
#pragma unroll
    for (int u = 0; u < 2; ++u) {
      int ncol = n0w + u * 16 + lo4;
      float* p = out + (size_t)mrow * N_DIM + ncol;
#pragma unroll
      for (int r = 0; r < 4; ++r)
        p[(size_t)r * N_DIM] = acc[mc][u][r] + bv[u];
    }
  }
}

// ---------------------------------------------------------------------------
extern "C" void kernel_launch(void* const* d_in, const int* in_sizes, int n_in,
                              void* d_out, int out_size, void* d_ws, size_t ws_size,
                              hipStream_t stream) {
  const float*    x    = (const float*)d_in[0];
  const uint32_t* q2   = (const uint32_t*)d_in[1];
  const float*    nm   = (const float*)d_in[2];
  const float*    bias = (const float*)d_in[3];
  float*          out  = (float*)d_out;
  uint4*          aws  = (uint4*)d_ws;   // 2 MiB: x as bf16 fragment chunks

  cvt_x_kernel<<<512, 256, 0, stream>>>(x, aws);
  gemm2bit_kernel<<<dim3(N_DIM / 128, M_DIM / 64), 256, 0, stream>>>(
      aws, q2, nm, bias, out);
}

// Round 17
// 156.873 us; speedup vs baseline: 1.2430x; 1.2430x over previous
//
#include <hip/hip_runtime.h>
#include <stdint.h>

// Problem: out[m][n] = sum_k x[m][k] * w[n][k] + bias[n]
//   M=256, N=16384, K=4096, w = dequant(2-bit, group=16 along k)
// Round 17: 32x32x16 MFMA consumers. r12 skeleton (61us best: producer/
// consumer, 4-deep ring, barrier/2-tiles, XOR swizzle, lgkm-only barrier).
//  - 2 CONSUMER waves, each 64m x 64n = 2x2 tiles of 32x32
//    (acc 2x2xf32x16 = 64 VGPR). Per block-tile: 8 ds_read (was 16),
//    16 MFMA (was 32), half the addressing VALU. A/LDS-write/dequant
//    traffic unchanged vs r12.
//  - 2 PRODUCER waves: r12 scheme at 2 groups/lane (r13's proven variant).
//  - B-frag (32x32x16): lane l needs col l&31, k=(l>>5)*8..+7 -> derived
//    from the same verified slot->(row,k) mapping. C/D: col=lane&31,
//    row=(reg&3)+8*(reg>>2)+4*(lane>>5)  [HW-verified m74/m101].
// Grid (256,2) x 256 thr; LDS 32KB; no launch_bounds VGPR squeeze.
#define M_DIM 256
#define N_DIM 16384
#define K_DIM 4096
#define BN 64
#define BK 64
#define NT (K_DIM / BK)   // 64 k-tiles

typedef __bf16 bf16x8 __attribute__((ext_vector_type(8)));
typedef float  f32x16 __attribute__((ext_vector_type(16)));

// fp32 -> bf16 bits, round-nearest-even (finite inputs)
__device__ __forceinline__ uint32_t f2bf(float f) {
  uint32_t u = __float_as_uint(f);
  return (u + 0x7fffu + ((u >> 16) & 1u)) >> 16;
}

// Barrier that waits ONLY on LDS ops -- global prefetches stay in flight.
#define LDS_BARRIER() \
  asm volatile("s_waitcnt lgkmcnt(0)\n\ts_barrier" ::: "memory")

// ---------------------------------------------------------------------------
// Kernel 1: x fp32 [256][4096] -> bf16 fragment-chunk order (unchanged).
// Chunk = (m-block of 16 rows) x (k-chunk of 32): 64 slots x 16B.
// Slot L holds row (L&15), k = (L>>4)*8 .. +7.
// ws uint4 index = (mb_glob*128 + kch)*64 + L.
// ---------------------------------------------------------------------------
__global__ __launch_bounds__(256) void cvt_x_kernel(const float* __restrict__ x,
                                                    uint4* __restrict__ ws) {
  int T = blockIdx.x * 256 + threadIdx.x;       // 0..131071
  int mb_glob = T >> 13;                        // 16 m-blocks
  int r       = T & 8191;
  int kch     = r >> 6;                         // 128 k-chunks
  int L       = r & 63;
  int row = mb_glob * 16 + (L & 15);
  int k   = kch * 32 + (L >> 4) * 8;
  const float* p = x + (size_t)row * K_DIM + k;
  float4 a = *(const float4*)p;
  float4 b = *(const float4*)(p + 4);
  uint4 o;
  o.x = f2bf(a.x) | (f2bf(a.y) << 16);
  o.y = f2bf(a.z) | (f2bf(a.w) << 16);
  o.z = f2bf(b.x) | (f2bf(b.y) << 16);
  o.w = f2bf(b.z) | (f2bf(b.w) << 16);
  ws[T] = o;
}

// ---------------------------------------------------------------------------
// Dequant 8 elems of one group (v_perm LUT, bit-identical to fmaf+f2bf path).
// ---------------------------------------------------------------------------
__device__ __forceinline__ uint4 deq8(uint32_t qx, uint32_t qy, uint32_t tlo,
                                      uint32_t thi) {
  uint32_t s0 = ((qx & 3u) | ((qx & 0xCu) << 14)) * 0x0202u + 0x01000100u;
  uint32_t s1 = (((qx >> 4) & 3u) | ((qx & 0xC0u) << 10)) * 0x0202u + 0x01000100u;
  uint32_t s2 = ((qy & 3u) | ((qy & 0xCu) << 14)) * 0x0202u + 0x01000100u;
  uint32_t s3 = (((qy >> 4) & 3u) | ((qy & 0xC0u) << 10)) * 0x0202u + 0x01000100u;
  uint4 r;
  r.x = __builtin_amdgcn_perm(thi, tlo, s0);
  r.y = __builtin_amdgcn_perm(thi, tlo, s1);
  r.z = __builtin_amdgcn_perm(thi, tlo, s2);
  r.w = __builtin_amdgcn_perm(thi, tlo, s3);
  return r;
}

// ---------------------------------------------------------------------------
// Kernel 2: grid (256,2), 256 threads, 4 waves: 2 consumers + 2 producers.
// LDS: Bb[4][512] -- tile T in buffer T&3 (8 chunks x 64 slots each).
// ---------------------------------------------------------------------------
__global__ __launch_bounds__(256) void gemm2bit_kernel(
    const uint4*    __restrict__ aws,  // A chunks (see cvt)
    const uint32_t* __restrict__ q2,   // [G][4] packed 2-bit (low byte crumbs)
    const float*    __restrict__ nrm,  // [G] group norms (f32)
    const float*    __restrict__ bias, // [N]
    float*          __restrict__ out)  // [256][16384] fp32
{
  __shared__ uint4 Bb[4][512];  // 4-deep tile ring, 32 KiB

  const int tid  = threadIdx.x;
  const int lane = tid & 63;
  const int w    = tid >> 6;    // 0..3
  const int lo4  = lane & 15;
  const int lo5  = lane & 31;
  const int hi   = lane >> 5;   // 0/1
  const int n0   = blockIdx.x * BN;
  const int m0   = blockIdx.y * 128;

  if (w < 2) {
    // ============ CONSUMER wave: 64m x 64n, 32x32x16 MFMA =================
    const int cw = w;            // m-panel: rows m0 + cw*64 .. +63

    // B read slots (per k-step ks): chunk = (ks>>1)*4 + u*2 + ((lane>>4)&1);
    // within: qd2k = (ks&1)*2 + hi, slot = qd2k*16 + (lo4 ^ qd2k).
    const int nb_off = ((lane >> 4) & 1) * 64;
    const int sE = hi * 16 + (lo4 ^ hi);              // ks even: qd2k = hi
    const int sO = (2 + hi) * 16 + (lo4 ^ (2 + hi));  // ks odd:  qd2k = 2+hi

    // A source: mb = blockIdx.y*8 + cw*4 + mt*2 + ((lane>>4)&1);
    // kch = T*2 + (ks>>1); slot = ((ks&1)*2 + hi)*16 + lo4.
    const uint4* pA = aws + (size_t)(blockIdx.y * 8 + cw * 4) * 8192 +
                      (size_t)((lane >> 4) & 1) * 8192 + hi * 16 + lo4;

    f32x16 acc[2][2];
#pragma unroll
    for (int mt = 0; mt < 2; ++mt)
#pragma unroll
      for (int u = 0; u < 2; ++u)
        acc[mt][u] = (f32x16)(0.f);

    uint4 afE[8], afO[8];   // [mt*4 + ks], ping-pong
#pragma unroll
    for (int mt = 0; mt < 2; ++mt)
#pragma unroll
      for (int ks = 0; ks < 4; ++ks)
        afE[mt * 4 + ks] =
            pA[(size_t)mt * 16384 + (ks >> 1) * 64 + (ks & 1) * 32];
    const uint4* pAp = pA + 128;   // next tile (2 chunks)
    LDS_BARRIER();   // matches producer prologue (tiles 0,1 written)

#define CONS_TILE(BUF, AFC, AFN, TNEXT)                                         \
    do {                                                                        \
      if ((TNEXT) < NT) {                                                       \
        _Pragma("unroll")                                                       \
        for (int mt = 0; mt < 2; ++mt)                                          \
          _Pragma("unroll")                                                     \
          for (int ks = 0; ks < 4; ++ks)                                        \
            AFN[mt * 4 + ks] =                                                  \
                pAp[(size_t)mt * 16384 + (ks >> 1) * 64 + (ks & 1) * 32];       \
      }                                                                         \
      pAp += 128;                                                               \
      __builtin_amdgcn_s_setprio(1);                                            \
      _Pragma("unroll")                                                         \
      for (int ks = 0; ks < 4; ++ks) {                                          \
        const int sk = (ks & 1) ? sO : sE;                                      \
        bf16x8 b0 = *(const bf16x8*)&Bb[BUF][(ks >> 1) * 256 + nb_off + sk];    \
        bf16x8 b1 =                                                             \
            *(const bf16x8*)&Bb[BUF][(ks >> 1) * 256 + 128 + nb_off + sk];      \
        _Pragma("unroll")                                                       \
        for (int mt = 0; mt < 2; ++mt) {                                        \
          bf16x8 av = __builtin_bit_cast(bf16x8, AFC[mt * 4 + ks]);             \
          acc[mt][0] = __builtin_amdgcn_mfma_f32_32x32x16_bf16(                 \
              av, b0, acc[mt][0], 0, 0, 0);                                     \
          acc[mt][1] = __builtin_amdgcn_mfma_f32_32x32x16_bf16(                 \
              av, b1, acc[mt][1], 0, 0, 0);                                     \
        }                                                                       \
      }                                                                         \
      __builtin_amdgcn_s_setprio(0);                                            \
    } while (0)

    for (int tp = 0; tp < NT; tp += 4) {
      CONS_TILE(0, afE, afO, tp + 1);
      CONS_TILE(1, afO, afE, tp + 2);
      LDS_BARRIER();
      CONS_TILE(2, afE, afO, tp + 3);
      CONS_TILE(3, afO, afE, tp + 4);
      LDS_BARRIER();
    }
#undef CONS_TILE

    // epilogue: C/D 32x32 layout col=lane&31 (n),
    // row = (r&3) + 8*(r>>2) + 4*hi (m)
    float bv[2];
#pragma unroll
    for (int u = 0; u < 2; ++u)
      bv[u] = bias[n0 + u * 32 + lo5];
#pragma unroll
    for (int mt = 0; mt < 2; ++mt)
#pragma unroll
      for (int u = 0; u < 2; ++u) {
        int ncol = n0 + u * 32 + lo5;
#pragma unroll
        for (int r = 0; r < 16; ++r) {
          int mrow = m0 + cw * 64 + mt * 32 + (r & 3) + 8 * (r >> 2) + 4 * hi;
          out[(size_t)mrow * N_DIM + ncol] = acc[mt][u][r] + bv[u];
        }
      }
  } else {
    // ======= PRODUCER wave: 2 groups/lane (rows ra, ra+16; same kg) ========
    const int pw    = w - 2;        // n-32-half 0..1
    const int kg    = lane & 3;     // k-group within BK (0..3)
    const int n_loc = lane >> 2;    // 0..15
    const int ra    = n0 + pw * 32 + n_loc;
    const int rb    = ra + 16;
    const int nba   = pw * 2;
    const int nbb   = pw * 2 + 1;
    const int qd2a  = (kg & 1) * 2;
    const int qd2b  = qd2a + 1;
    const int ba    = ((kg >> 1) * 4 + nba) * 64;
    const int bb    = ((kg >> 1) * 4 + nbb) * 64;
    const int sAa = ba + qd2a * 16 + (n_loc ^ qd2a);
    const int sBa = ba + qd2b * 16 + (n_loc ^ qd2b);
    const int sAb = bb + qd2a * 16 + (n_loc ^ qd2a);
    const int sBb = bb + qd2b * 16 + (n_loc ^ qd2b);

    const uint32_t* pqa = q2 + ((size_t)ra * 256 + kg) * 4;  // +16 words/tile
    const uint32_t* pqb = q2 + ((size_t)rb * 256 + kg) * 4;
    const float*    pna = nrm + (size_t)ra * 256 + kg;       // +4/tile
    const float*    pnb = nrm + (size_t)rb * 256 + kg;

#define DEQ_G(WB, Q, NV, SA, SB)                                                \
    do {                                                                        \
      float a2_ = (NV) * (2.0f / 3.0f);                                         \
      uint32_t tlo_ = f2bf(-(NV)) | (f2bf(fmaf(1.0f, a2_, -(NV))) << 16);       \
      uint32_t thi_ = f2bf(fmaf(2.0f, a2_, -(NV))) |                            \
                      (f2bf(fmaf(3.0f, a2_, -(NV))) << 16);                     \
      Bb[WB][SA] = deq8((Q).x, (Q).y, tlo_, thi_);                              \
      Bb[WB][SB] = deq8((Q).z, (Q).w, tlo_, thi_);                              \
    } while (0)
#define DEQ_TILE2(WB, QA, NA, QB, NB)                                           \
    do {                                                                        \
      DEQ_G(WB, QA, NA, sAa, sBa);                                              \
      DEQ_G(WB, QB, NB, sAb, sBb);                                              \
    } while (0)

    // prologue: deq tiles 0,1 -> bufs 0,1; hold (2,3)->E, (4,5)->O in flight
    {
      uint4 t0a = *(const uint4*)pqa;         float y0a = pna[0];
      uint4 t0b = *(const uint4*)pqb;         float y0b = pnb[0];
      uint4 t1a = *(const uint4*)(pqa + 16);  float y1a = pna[4];
      uint4 t1b = *(const uint4*)(pqb + 16);  float y1b = pnb[4];
      DEQ_TILE2(0, t0a, y0a, t0b, y0b);
      DEQ_TILE2(1, t1a, y1a, t1b, y1b);
    }
    uint4 qE0a = *(const uint4*)(pqa + 32);  float nE0a = pna[8];
    uint4 qE0b = *(const uint4*)(pqb + 32);  float nE0b = pnb[8];
    uint4 qE1a = *(const uint4*)(pqa + 48);  float nE1a = pna[12];
    uint4 qE1b = *(const uint4*)(pqb + 48);  float nE1b = pnb[12];
    uint4 qO0a = *(const uint4*)(pqa + 64);  float nO0a = pna[16];
    uint4 qO0b = *(const uint4*)(pqb + 64);  float nO0b = pnb[16];
    uint4 qO1a = *(const uint4*)(pqa + 80);  float nO1a = pna[20];
    uint4 qO1b = *(const uint4*)(pqb + 80);  float nO1b = pnb[20];
    const uint32_t* pqla = pqa + 96;   // tile 6; +32 words per phase
    const uint32_t* pqlb = pqb + 96;
    const float*    pnla = pna + 24;
    const float*    pnlb = pnb + 24;
    LDS_BARRIER();

    for (int tp = 0; tp < NT; tp += 4) {
      // phase A: write tiles tp+2,tp+3 -> bufs 2,3; reload E = tp+6,tp+7
      if (tp + 2 < NT) {
        DEQ_TILE2(2, qE0a, nE0a, qE0b, nE0b);
        DEQ_TILE2(3, qE1a, nE1a, qE1b, nE1b);
      }
      if (tp + 6 < NT) {
        qE0a = *(const uint4*)pqla;        nE0a = pnla[0];
        qE0b = *(const uint4*)pqlb;        nE0b = pnlb[0];
        qE1a = *(const uint4*)(pqla + 16); nE1a = pnla[4];
        qE1b = *(const uint4*)(pqlb + 16); nE1b = pnlb[4];
      }
      pqla += 32; pqlb += 32; pnla += 8; pnlb += 8;
      LDS_BARRIER();
      // phase B: write tiles tp+4,tp+5 -> bufs 0,1; reload O = tp+8,tp+9
      if (tp + 4 < NT) {
        DEQ_TILE2(0, qO0a, nO0a, qO0b, nO0b);
        DEQ_TILE2(1, qO1a, nO1a, qO1b, nO1b);
      }
      if (tp + 8 < NT) {
        qO0a = *(const uint4*)pqla;        nO0a = pnla[0];
        qO0b = *(const uint4*)pqlb;        nO0b = pnlb[0];
        qO1a = *(const uint4*)(pqla + 16); nO1a = pnla[4];
        qO1b = *(const uint4*)(pqlb + 16); nO1b = pnlb[4];
      }
      pqla += 32; pqlb += 32; pnla += 8; pnlb += 8;
      LDS_BARRIER();
    }
#undef DEQ_TILE2
#undef DEQ_G
  }
}

// ---------------------------------------------------------------------------
extern "C" void kernel_launch(void* const* d_in, const int* in_sizes, int n_in,
                              void* d_out, int out_size, void* d_ws, size_t ws_size,
                              hipStream_t stream) {
  const float*    x    = (const float*)d_in[0];
  const uint32_t* q2   = (const uint32_t*)d_in[1];
  const float*    nm   = (const float*)d_in[2];
  const float*    bias = (const float*)d_in[3];
  float*          out  = (float*)d_out;
  uint4*          aws  = (uint4*)d_ws;   // 2 MiB: x as bf16 fragment chunks

  cvt_x_kernel<<<512, 256, 0, stream>>>(x, aws);
  gemm2bit_kernel<<<dim3(N_DIM / BN, 2), 256, 0, stream>>>(aws, q2, nm, bias, out);
}